// Round 16
// baseline (864.593 us; speedup 1.0000x reference)
//
#include <hip/hip_runtime.h>
#include <cstdint>

#define NGRAPH 128
#define OUT_C 16
#define NEG 0.2f
#define NB_MAX 512      // buckets of 256 dst nodes; N=100K -> 391 buckets
#define BSH 8           // bucket shift
#define BSZ 256         // bucket size
#define CAP 8192        // bbuf slots per bucket (expected max ~4800)
#define BINCH 2048      // edges per k_bin block (8 per thread)

typedef unsigned int uint;
typedef unsigned short ushort;
typedef unsigned char uchar;
typedef __attribute__((ext_vector_type(8))) short bf16x8;
typedef __attribute__((ext_vector_type(4))) float f32x4;
typedef __attribute__((ext_vector_type(2))) float f32x2;

union U4B { uint4 u; bf16x8 v; };

__device__ __forceinline__ ushort f2bf(float f) {
  uint u = __float_as_uint(f);
  uint r = (u + 0x7FFF + ((u >> 16) & 1)) >> 16;   // RNE
  return (ushort)r;
}

__device__ __forceinline__ int wave_incl_scan_i(int v) {
  int lane = threadIdx.x & 63;
#pragma unroll
  for (int off = 1; off < 64; off <<= 1) {
    int u = __shfl_up(v, off, 64);
    if (lane >= off) v += u;
  }
  return v;
}

// ---------------- k_bin: single-pass edge binning (regs cache s,d); + W1/W2 prep ----------------
__global__ void k_bin(const int* __restrict__ ei,
                      const float* __restrict__ W1, const float* __restrict__ W2,
                      ushort* __restrict__ Wt1, ushort* __restrict__ Wt2,
                      int E, int Etot, int NB, int nbin,
                      int* __restrict__ bcur, uint* __restrict__ bbuf) {
  if (blockIdx.x >= (uint)nbin) {
    int t2 = (blockIdx.x - nbin) * 256 + threadIdx.x;
    if (t2 < 16384) {
      int n = t2 >> 7, k = t2 & 127;
      Wt1[t2] = f2bf(W1[k * 128 + n]);
    } else {
      int u = t2 - 16384;
      int n = u >> 7, k = u & 127;
      Wt2[u] = f2bf(W2[k * 32 + n]);
    }
    return;
  }
  __shared__ int h[NB_MAX];
  __shared__ int baseo[NB_MAX];
  int t = threadIdx.x;
  for (int b = t; b < NB; b += 256) h[b] = 0;
  int cbase = blockIdx.x * BINCH;
  int myd[8], mys[8];
#pragma unroll
  for (int j = 0; j < 8; j++) {
    int e = cbase + j * 256 + t;
    if (e < Etot) {
      if (e < E) { mys[j] = ei[e]; myd[j] = ei[E + e]; }
      else { mys[j] = e - E; myd[j] = e - E; }
    } else { myd[j] = -1; mys[j] = 0; }
  }
  __syncthreads();
#pragma unroll
  for (int j = 0; j < 8; j++)
    if (myd[j] >= 0) atomicAdd(&h[myd[j] >> BSH], 1);
  __syncthreads();
  for (int b = t; b < NB; b += 256) {
    int c = h[b];
    baseo[b] = c ? atomicAdd(&bcur[b], c) : 0;
    h[b] = 0;
  }
  __syncthreads();
#pragma unroll
  for (int j = 0; j < 8; j++) {
    if (myd[j] >= 0) {
      int b = myd[j] >> BSH;
      int r = atomicAdd(&h[b], 1);
      bbuf[(size_t)b * CAP + baseo[b] + r] =
          ((uint)(myd[j] & (BSZ - 1)) << 17) | (uint)mys[j];
    }
  }
}

// ---------------- k_bg: blocks [0,NB) = CSR build; blocks [NB,..) = GEMM1+att1 ----------------
__global__ void k_bg(const uint* __restrict__ bbuf, const int* __restrict__ bcur,
                     int NB, int N, int* __restrict__ offs, int* __restrict__ ssrc,
                     const float* __restrict__ x, const ushort* __restrict__ Wt,
                     const float* __restrict__ nw, const float* __restrict__ att_s,
                     const float* __restrict__ att_d, uchar* __restrict__ hb1,
                     float* __restrict__ asrc, float* __restrict__ adst) {
  __shared__ int sst[NB_MAX + 1];
  __shared__ int wsum2[4];
  __shared__ int deg[BSZ];
  if (blockIdx.x < (uint)NB) {
    int t = threadIdx.x, lane = t & 63, wid = t >> 6;
    int v0 = (2 * t < NB) ? bcur[2 * t] : 0;
    int v1 = (2 * t + 1 < NB) ? bcur[2 * t + 1] : 0;
    int s = v0 + v1;
    int sv = wave_incl_scan_i(s);
    if (lane == 63) wsum2[wid] = sv;
    deg[t] = 0;
    __syncthreads();
    if (t == 0) {
      int r = 0;
#pragma unroll
      for (int k = 0; k < 4; k++) { int x2 = wsum2[k]; wsum2[k] = r; r += x2; }
    }
    __syncthreads();
    int excl = wsum2[wid] + sv - s;
    sst[2 * t] = excl;
    sst[2 * t + 1] = excl + v0;
    if (t == 255) sst[512] = excl + v0 + v1;
    __syncthreads();
    int b = blockIdx.x;
    int ebeg = sst[b], eend = sst[b + 1];
    int cnt = eend - ebeg;
    for (int i = t; i < cnt; i += BSZ)
      atomicAdd(&deg[bbuf[(size_t)b * CAP + i] >> 17], 1);
    __syncthreads();
    int v = deg[t];
    int sv2 = wave_incl_scan_i(v);
    if (lane == 63) wsum2[wid] = sv2;
    __syncthreads();
    if (t == 0) {
      int r = 0;
#pragma unroll
      for (int k = 0; k < 4; k++) { int x2 = wsum2[k]; wsum2[k] = r; r += x2; }
    }
    __syncthreads();
    int excl2 = wsum2[wid] + sv2 - v;
    int node = (b << BSH) + t;
    if (node < N) offs[node] = ebeg + excl2;
    if (b == 0 && t == 0) offs[N] = sst[512];
    __syncthreads();
    deg[t] = excl2;
    __syncthreads();
    for (int i = t; i < cnt; i += BSZ) {
      uint rec = bbuf[(size_t)b * CAP + i];
      int r = atomicAdd(&deg[rec >> 17], 1);
      ssrc[ebeg + r] = (int)(rec & 0x1FFFF);
    }
    return;
  }
  // ---- gemm1 path (operand-swapped MFMA: D[channel][node]) ----
  int bid = blockIdx.x - NB;
  int wv = threadIdx.x >> 6, l = threadIdx.x & 63;
  int lg = l >> 4, lr = l & 15;
  int row0 = bid * 64 + wv * 16;
  int node = row0 + lr;
  bool valid = node < N;
  float sc = valid ? nw[node] : 0.f;
  bf16x8 xfr[4];
  const float* xr = x + (size_t)node * 128;
#pragma unroll
  for (int kc = 0; kc < 4; kc++) {
    float v[8];
    if (valid) {
      float4 q0 = *reinterpret_cast<const float4*>(xr + kc * 32 + lg * 8);
      float4 q1 = *reinterpret_cast<const float4*>(xr + kc * 32 + lg * 8 + 4);
      v[0] = q0.x; v[1] = q0.y; v[2] = q0.z; v[3] = q0.w;
      v[4] = q1.x; v[5] = q1.y; v[6] = q1.z; v[7] = q1.w;
    } else {
#pragma unroll
      for (int j = 0; j < 8; j++) v[j] = 0.f;
    }
    U4B a;
    uint pk0 = (uint)f2bf(v[0] * sc) | ((uint)f2bf(v[1] * sc) << 16);
    uint pk1 = (uint)f2bf(v[2] * sc) | ((uint)f2bf(v[3] * sc) << 16);
    uint pk2 = (uint)f2bf(v[4] * sc) | ((uint)f2bf(v[5] * sc) << 16);
    uint pk3 = (uint)f2bf(v[6] * sc) | ((uint)f2bf(v[7] * sc) << 16);
    a.u = make_uint4(pk0, pk1, pk2, pk3);
    xfr[kc] = a.v;
  }
  float pS[4] = {}, pD[4] = {};
#pragma unroll
  for (int ct = 0; ct < 8; ct++) {
    f32x4 acc = {0.f, 0.f, 0.f, 0.f};
    const ushort* wrow = Wt + (size_t)(ct * 16 + lr) * 128;
#pragma unroll
    for (int kc = 0; kc < 4; kc++) {
      U4B bfr;
      bfr.u = *reinterpret_cast<const uint4*>(wrow + kc * 32 + lg * 8);
      acc = __builtin_amdgcn_mfma_f32_16x16x32_bf16(bfr.v, xfr[kc], acc, 0, 0, 0);
    }
    int c0 = ct * 16 + lg * 4;
    if (valid) {
      uint u8 = (uint)__builtin_amdgcn_cvt_pk_fp8_f32(acc[0], acc[1], 0, false);
      u8 = (uint)__builtin_amdgcn_cvt_pk_fp8_f32(acc[2], acc[3], u8, true);
      *reinterpret_cast<uint*>(hb1 + (size_t)node * 128 + c0) = u8;
    }
    float4 as4 = *reinterpret_cast<const float4*>(att_s + c0);
    float4 ad4 = *reinterpret_cast<const float4*>(att_d + c0);
    int h = ct >> 1;
    pS[h] += acc[0] * as4.x + acc[1] * as4.y + acc[2] * as4.z + acc[3] * as4.w;
    pD[h] += acc[0] * ad4.x + acc[1] * ad4.y + acc[2] * ad4.z + acc[3] * ad4.w;
  }
#pragma unroll
  for (int off = 16; off < 64; off <<= 1) {
#pragma unroll
    for (int h = 0; h < 4; h++) {
      pS[h] += __shfl_xor(pS[h], off, 64);
      pD[h] += __shfl_xor(pD[h], off, 64);
    }
  }
  if (lg == 0 && valid) {
    *reinterpret_cast<float4*>(asrc + node * 4) = make_float4(pS[0], pS[1], pS[2], pS[3]);
    *reinterpret_cast<float4*>(adst + node * 4) = make_float4(pD[0], pD[1], pD[2], pD[3]);
  }
}

// ---- fused layer-1 aggregation + layer-2 GEMM (MFMA, wave-0 tail) + att2 ----
__global__ void k_aggr1(const int* __restrict__ offs, const int* __restrict__ ssrc,
                        const uchar* __restrict__ hb, const float* __restrict__ asrc,
                        const float* __restrict__ adst, const float* __restrict__ bias,
                        const ushort* __restrict__ Wt2, const float* __restrict__ as2,
                        const float* __restrict__ ad2, uchar* __restrict__ hb2,
                        float* __restrict__ asrc2, float* __restrict__ adst2, int N) {
  __shared__ ushort rowl[4][160];    // bf16 out1 rows, stride 320B == 16 words mod 32
  int tid = threadIdx.x;
  int wv = tid >> 6, l = tid & 63;
  int d = blockIdx.x * 4 + wv;
  int dc = min(d, N - 1);
  int slot = l >> 3;       // 0..7 edge slot
  int cb = l & 7;          // channel block: ch cb*16 .. +15
  int h = cb >> 1;         // head of this lane's channels
  float ad = adst[dc * 4 + h];
  int beg = offs[dc], end = offs[dc + 1];
  float a[16] = {};
  float ds = 0.f;
  for (int i = beg; i < end; i += 8) {
    int e = i + slot;
    int ec = min(e, end - 1);
    int s = ssrc[ec];
    float xv = asrc[s * 4 + h] + ad;
    xv = xv > 0.f ? xv : NEG * xv;
    float w = __expf(xv);
    w = (e < end) ? w : 0.f;
    uint4 p = *reinterpret_cast<const uint4*>(hb + (size_t)s * 128 + cb * 16);
    uint pu[4] = {p.x, p.y, p.z, p.w};
#pragma unroll
    for (int q = 0; q < 4; q++) {
      f32x2 f0 = __builtin_amdgcn_cvt_pk_f32_fp8(pu[q], false);
      f32x2 f1 = __builtin_amdgcn_cvt_pk_f32_fp8(pu[q], true);
      a[q * 4 + 0] += w * f0.x;
      a[q * 4 + 1] += w * f0.y;
      a[q * 4 + 2] += w * f1.x;
      a[q * 4 + 3] += w * f1.y;
    }
    ds += w;
  }
  int b3 = (l >> 3) & 1, b4 = (l >> 4) & 1, b5 = (l >> 5) & 1;
  float t8[8];
#pragma unroll
  for (int r = 0; r < 8; r++) {
    float send = b3 ? a[r] : a[r + 8];
    float recv = __shfl_xor(send, 8, 64);
    t8[r] = (b3 ? a[r + 8] : a[r]) + recv;
  }
  float t4[4];
#pragma unroll
  for (int r = 0; r < 4; r++) {
    float send = b4 ? t8[r] : t8[r + 4];
    float recv = __shfl_xor(send, 16, 64);
    t4[r] = (b4 ? t8[r + 4] : t8[r]) + recv;
  }
  float t2[2];
#pragma unroll
  for (int r = 0; r < 2; r++) {
    float send = b5 ? t4[r] : t4[r + 2];
    float recv = __shfl_xor(send, 32, 64);
    t2[r] = (b5 ? t4[r + 2] : t4[r]) + recv;
  }
  ds += __shfl_xor(ds, 8, 64);
  ds += __shfl_xor(ds, 16, 64);
  ds += __shfl_xor(ds, 32, 64);
  float inv = 1.f / (ds > 0.f ? ds : 1.f);
  int c0 = cb * 16 + b3 * 8 + b4 * 4 + b5 * 2;
  float r0 = t2[0] * inv + bias[c0];
  float r1 = t2[1] * inv + bias[c0 + 1];
  r0 = r0 > 0.f ? r0 : expm1f(r0);
  r1 = r1 > 0.f ? r1 : expm1f(r1);
  *reinterpret_cast<uint*>(&rowl[wv][c0]) = (uint)f2bf(r0) | ((uint)f2bf(r1) << 16);
  __syncthreads();
  if (wv != 0) return;
  // ---- gemm2 + att2 on the block's 4 rows (wave 0 only) ----
  int lg = l >> 4, lr = l & 15;
  int rsel = lr & 3;
  bf16x8 bfrag[4];
#pragma unroll
  for (int kc = 0; kc < 4; kc++) {
    U4B bb;
    bb.u = *reinterpret_cast<const uint4*>(&rowl[rsel][kc * 32 + lg * 8]);
    bfrag[kc] = bb.v;
  }
  int dd = blockIdx.x * 4 + lr;      // valid only for lr<4
  bool vs = (lr < 4) && (dd < N);
  float pS = 0.f, pD = 0.f;
#pragma unroll
  for (int ct = 0; ct < 2; ct++) {
    f32x4 acc = {0.f, 0.f, 0.f, 0.f};
    const ushort* wrow = Wt2 + (size_t)(ct * 16 + lr) * 128;
#pragma unroll
    for (int kc = 0; kc < 4; kc++) {
      U4B bfr;
      bfr.u = *reinterpret_cast<const uint4*>(wrow + kc * 32 + lg * 8);
      acc = __builtin_amdgcn_mfma_f32_16x16x32_bf16(bfr.v, bfrag[kc], acc, 0, 0, 0);
    }
    int cg = ct * 16 + lg * 4;
    if (vs) {
      uint u8 = (uint)__builtin_amdgcn_cvt_pk_fp8_f32(acc[0], acc[1], 0, false);
      u8 = (uint)__builtin_amdgcn_cvt_pk_fp8_f32(acc[2], acc[3], u8, true);
      *reinterpret_cast<uint*>(hb2 + (size_t)dd * 32 + cg) = u8;
    }
    float4 as4 = *reinterpret_cast<const float4*>(as2 + cg);
    float4 ad4 = *reinterpret_cast<const float4*>(ad2 + cg);
    pS += acc[0] * as4.x + acc[1] * as4.y + acc[2] * as4.z + acc[3] * as4.w;
    pD += acc[0] * ad4.x + acc[1] * ad4.y + acc[2] * ad4.z + acc[3] * ad4.w;
  }
  pS += __shfl_xor(pS, 16, 64);
  pS += __shfl_xor(pS, 32, 64);
  pD += __shfl_xor(pD, 16, 64);
  pD += __shfl_xor(pD, 32, 64);
  if (vs && lg == 0) { asrc2[dd] = pS; adst2[dd] = pD; }
}

// ---- layer-2 aggregation + atomic global pooling + last-block FC ----
// Each dst's ELU output is atomically accumulated into pooled[graph][ch].
// The LAST block (single atomic ticket, no spinning) computes mean + FC -> out.
__global__ void k_aggr2(const int* __restrict__ offs, const int* __restrict__ ssrc,
                        const uchar* __restrict__ hb, const float* __restrict__ asrc,
                        const float* __restrict__ adst, const float* __restrict__ bias,
                        const int* __restrict__ batch, const float* __restrict__ fcW,
                        const float* __restrict__ fcb, float* __restrict__ pooled,
                        int* __restrict__ counter, float* __restrict__ out,
                        int N, int nblk) {
  __shared__ float pl[NGRAPH * 32];
  __shared__ float cnts[NGRAPH];
  __shared__ int lastf;
  int wid = threadIdx.x >> 6, l = threadIdx.x & 63;
  int d = blockIdx.x * 4 + wid;
  if (d < N) {
    int slot = l >> 2;       // 0..15 edge slot
    int k = l & 3;           // channel block: ch k*8 .. +7
    float ad = adst[d];
    int beg = offs[d], end = offs[d + 1];
    float a[8] = {};
    float ds = 0.f;
    for (int i = beg; i < end; i += 16) {
      int e = i + slot;
      int ec = min(e, end - 1);
      int s = ssrc[ec];
      float xv = asrc[s] + ad;
      xv = xv > 0.f ? xv : NEG * xv;
      float w = __expf(xv);
      w = (e < end) ? w : 0.f;
      uint2 p = *reinterpret_cast<const uint2*>(hb + (size_t)s * 32 + k * 8);
      f32x2 f0 = __builtin_amdgcn_cvt_pk_f32_fp8(p.x, false);
      f32x2 f1 = __builtin_amdgcn_cvt_pk_f32_fp8(p.x, true);
      f32x2 f2 = __builtin_amdgcn_cvt_pk_f32_fp8(p.y, false);
      f32x2 f3 = __builtin_amdgcn_cvt_pk_f32_fp8(p.y, true);
      a[0] += w * f0.x; a[1] += w * f0.y; a[2] += w * f1.x; a[3] += w * f1.y;
      a[4] += w * f2.x; a[5] += w * f2.y; a[6] += w * f3.x; a[7] += w * f3.y;
      ds += w;
    }
    int b2 = (l >> 2) & 1, b3 = (l >> 3) & 1, b4 = (l >> 4) & 1;
    float t4[4];
#pragma unroll
    for (int r = 0; r < 4; r++) {
      float send = b2 ? a[r] : a[r + 4];
      float recv = __shfl_xor(send, 4, 64);
      t4[r] = (b2 ? a[r + 4] : a[r]) + recv;
    }
    float t2[2];
#pragma unroll
    for (int r = 0; r < 2; r++) {
      float send = b3 ? t4[r] : t4[r + 2];
      float recv = __shfl_xor(send, 8, 64);
      t2[r] = (b3 ? t4[r + 2] : t4[r]) + recv;
    }
    float send = b4 ? t2[0] : t2[1];
    float recv = __shfl_xor(send, 16, 64);
    float t1 = (b4 ? t2[1] : t2[0]) + recv;
    t1 += __shfl_xor(t1, 32, 64);
    ds += __shfl_xor(ds, 4, 64);
    ds += __shfl_xor(ds, 8, 64);
    ds += __shfl_xor(ds, 16, 64);
    ds += __shfl_xor(ds, 32, 64);
    if (l < 32) {
      int c = k * 8 + b2 * 4 + b3 * 2 + b4;
      float r = t1 / ds + bias[c];
      r = r > 0.f ? r : expm1f(r);
      int g = batch[d];
      atomicAdd(&pooled[g * 32 + c], r);    // device-scope
    }
  }
  __syncthreads();
  if (threadIdx.x == 0) {
    __threadfence();                         // release our pooled adds
    int v = atomicAdd(counter, 1);
    lastf = (v == nblk - 1);
  }
  __syncthreads();
  if (!lastf) return;
  // ---- last block: mean + FC ----
  __threadfence();                           // acquire
  int t = threadIdx.x;
  for (int i = t; i < NGRAPH * 32; i += 256)
    pl[i] = atomicAdd(&pooled[i], 0.f);      // coherent read via RMW
  if (t < NGRAPH) {
    int g = t;
    int lo = 0, hi = N;
    while (lo < hi) { int mid = (lo + hi) >> 1; if (batch[mid] < g) lo = mid + 1; else hi = mid; }
    int bg = lo;
    hi = N;
    while (lo < hi) { int mid = (lo + hi) >> 1; if (batch[mid] < g + 1) lo = mid + 1; else hi = mid; }
    cnts[g] = fmaxf((float)(lo - bg), 1.f);
  }
  __syncthreads();
  for (int pair = t; pair < NGRAPH * OUT_C; pair += 256) {
    int g = pair >> 4, oc = pair & 15;
    float ic = 1.f / cnts[g];
    float acc = fcb[oc];
#pragma unroll
    for (int cc = 0; cc < 32; cc++)
      acc += pl[g * 32 + cc] * ic * fcW[cc * 16 + oc];
    out[g * 16 + oc] = acc;
  }
}

// ---------------- host launch ----------------
extern "C" void kernel_launch(void* const* d_in, const int* in_sizes, int n_in,
                              void* d_out, int out_size, void* d_ws, size_t ws_size,
                              hipStream_t stream) {
  const float* x     = (const float*)d_in[0];
  const int*   ei    = (const int*)d_in[1];
  const int*   batch = (const int*)d_in[2];
  const float* nw    = (const float*)d_in[3];
  const float* W1    = (const float*)d_in[4];
  const float* as1w  = (const float*)d_in[5];
  const float* ad1w  = (const float*)d_in[6];
  const float* b1    = (const float*)d_in[7];
  const float* W2    = (const float*)d_in[8];
  const float* as2w  = (const float*)d_in[9];
  const float* ad2w  = (const float*)d_in[10];
  const float* b2    = (const float*)d_in[11];
  const float* fcW   = (const float*)d_in[12];
  const float* fcb   = (const float*)d_in[13];
  float* out = (float*)d_out;

  const int N = in_sizes[0] / 128;
  const int E = in_sizes[1] / 2;
  const int Etot = E + N;
  const int NB = (N + BSZ - 1) >> BSH;

  char* w = (char*)d_ws;
  size_t ofs = 0;
  auto alloc = [&](size_t bytes) {
    char* p = w + ofs;
    ofs += (bytes + 255) & ~(size_t)255;
    return p;
  };
  uchar*  hb1    = (uchar*)alloc((size_t)N * 128);        // fp8 layer-1 features
  uchar*  hb2    = (uchar*)alloc((size_t)N * 32);         // fp8 layer-2 features
  float*  asrc1  = (float*)alloc((size_t)N * 4 * 4);
  float*  adst1  = (float*)alloc((size_t)N * 4 * 4);
  float*  asrc2  = (float*)alloc((size_t)N * 4);
  float*  adst2  = (float*)alloc((size_t)N * 4);
  ushort* Wt1    = (ushort*)alloc(16384 * 2);
  ushort* Wt2    = (ushort*)alloc(4096 * 2);
  // zeroed region: bcur (NB) | counter (1, padded to 8) | pooled (NGRAPH*32 floats)
  int*    zbase  = (int*)alloc((size_t)(NB + 8 + NGRAPH * 32) * 4);
  int*    bcur   = zbase;
  int*    counter= zbase + NB;
  float*  pooled = (float*)(zbase + NB + 8);
  int*    offs   = (int*)alloc((size_t)(N + 1) * 4);
  uint*   bbuf   = (uint*)alloc((size_t)NB * CAP * 4);
  int*    ssrc   = (int*)alloc((size_t)Etot * 4);

  hipMemsetAsync(zbase, 0, (size_t)(NB + 8 + NGRAPH * 32) * 4, stream);

  // binned CSR: hist+scatter (+W1/W2 prep folded in)
  const int nbin = (Etot + BINCH - 1) / BINCH;
  k_bin<<<nbin + 80, 256, 0, stream>>>(ei, W1, W2, Wt1, Wt2, E, Etot, NB, nbin, bcur, bbuf);

  // build ‖ gemm1 (independent): blocks [0,NB) build CSR, rest run GEMM1+att1
  const int ngemm1 = (N + 63) / 64;
  k_bg<<<NB + ngemm1, 256, 0, stream>>>(bbuf, bcur, NB, N, offs, ssrc,
                                        x, Wt1, nw, as1w, ad1w, hb1, asrc1, adst1);

  // fused: layer-1 aggregation + layer-2 GEMM (wave-0 MFMA tail) + att2
  k_aggr1<<<(N + 3) / 4, 256, 0, stream>>>(offs, ssrc, hb1, asrc1, adst1, b1,
                                           Wt2, as2w, ad2w, hb2, asrc2, adst2, N);

  // layer-2 aggregation + pooling + last-block FC
  const int nblk2 = (N + 3) / 4;
  k_aggr2<<<nblk2, 256, 0, stream>>>(offs, ssrc, hb2, asrc2, adst2, b2,
                                     batch, fcW, fcb, pooled, counter, out, N, nblk2);
}

// Round 17
// 311.871 us; speedup vs baseline: 2.7723x; 2.7723x over previous
//
#include <hip/hip_runtime.h>
#include <cstdint>

#define NGRAPH 128
#define NEG 0.2f
#define NB_MAX 512      // buckets of 256 dst nodes; N=100K -> 391 buckets
#define BSH 8           // bucket shift
#define BSZ 256         // bucket size
#define CAP 8192        // bbuf slots per bucket (expected max ~4800)

typedef unsigned int uint;
typedef unsigned short ushort;
typedef unsigned char uchar;
typedef __attribute__((ext_vector_type(8))) short bf16x8;
typedef __attribute__((ext_vector_type(4))) float f32x4;
typedef __attribute__((ext_vector_type(2))) float f32x2;

union U4B { uint4 u; bf16x8 v; };

__device__ __forceinline__ ushort f2bf(float f) {
  uint u = __float_as_uint(f);
  uint r = (u + 0x7FFF + ((u >> 16) & 1)) >> 16;   // RNE
  return (ushort)r;
}

__device__ __forceinline__ int wave_incl_scan_i(int v) {
  int lane = threadIdx.x & 63;
#pragma unroll
  for (int off = 1; off < 64; off <<= 1) {
    int u = __shfl_up(v, off, 64);
    if (lane >= off) v += u;
  }
  return v;
}

// ---------------- k_bin: per-block LDS hist -> bucket alloc -> scatter; + W1/W2 prep ----------------
__global__ void k_bin(const int* __restrict__ ei,
                      const float* __restrict__ W1, const float* __restrict__ W2,
                      ushort* __restrict__ Wt1, ushort* __restrict__ Wt2,
                      int E, int Etot, int NB, int nbin,
                      int* __restrict__ bcur, uint* __restrict__ bbuf) {
  if (blockIdx.x >= (uint)nbin) {
    int t2 = (blockIdx.x - nbin) * 256 + threadIdx.x;
    if (t2 < 16384) {
      int n = t2 >> 7, k = t2 & 127;
      Wt1[t2] = f2bf(W1[k * 128 + n]);
    } else {
      int u = t2 - 16384;
      int n = u >> 7, k = u & 127;
      Wt2[u] = f2bf(W2[k * 32 + n]);
    }
    return;
  }
  __shared__ int h[NB_MAX];
  __shared__ int baseo[NB_MAX];
  int t = threadIdx.x;
  for (int b = t; b < NB; b += 256) h[b] = 0;
  __syncthreads();
  int cbase = blockIdx.x * 4096;
  int cend = min(cbase + 4096, Etot);
  for (int e = cbase + t; e < cend; e += 256) {
    int d = (e < E) ? ei[E + e] : (e - E);
    atomicAdd(&h[d >> BSH], 1);
  }
  __syncthreads();
  for (int b = t; b < NB; b += 256) {
    int c = h[b];
    baseo[b] = c ? atomicAdd(&bcur[b], c) : 0;
    h[b] = 0;
  }
  __syncthreads();
  for (int e = cbase + t; e < cend; e += 256) {
    int s, d;
    if (e < E) { s = ei[e]; d = ei[E + e]; } else { s = e - E; d = s; }
    int b = d >> BSH;
    int r = atomicAdd(&h[b], 1);
    bbuf[(size_t)b * CAP + baseo[b] + r] = ((uint)(d & (BSZ - 1)) << 17) | (uint)s;
  }
}

// ---------------- k_bg: blocks [0,NB) = CSR build; blocks [NB,..) = GEMM1+att1 ----------------
__global__ void k_bg(const uint* __restrict__ bbuf, const int* __restrict__ bcur,
                     int NB, int N, int* __restrict__ offs, int* __restrict__ ssrc,
                     const float* __restrict__ x, const ushort* __restrict__ Wt,
                     const float* __restrict__ nw, const float* __restrict__ att_s,
                     const float* __restrict__ att_d, uchar* __restrict__ hb1,
                     float* __restrict__ asrc, float* __restrict__ adst) {
  __shared__ int sst[NB_MAX + 1];
  __shared__ int wsum2[4];
  __shared__ int deg[BSZ];
  if (blockIdx.x < (uint)NB) {
    int t = threadIdx.x, lane = t & 63, wid = t >> 6;
    int v0 = (2 * t < NB) ? bcur[2 * t] : 0;
    int v1 = (2 * t + 1 < NB) ? bcur[2 * t + 1] : 0;
    int s = v0 + v1;
    int sv = wave_incl_scan_i(s);
    if (lane == 63) wsum2[wid] = sv;
    deg[t] = 0;
    __syncthreads();
    if (t == 0) {
      int r = 0;
#pragma unroll
      for (int k = 0; k < 4; k++) { int x2 = wsum2[k]; wsum2[k] = r; r += x2; }
    }
    __syncthreads();
    int excl = wsum2[wid] + sv - s;
    sst[2 * t] = excl;
    sst[2 * t + 1] = excl + v0;
    if (t == 255) sst[512] = excl + v0 + v1;
    __syncthreads();
    int b = blockIdx.x;
    int ebeg = sst[b], eend = sst[b + 1];
    int cnt = eend - ebeg;
    for (int i = t; i < cnt; i += BSZ)
      atomicAdd(&deg[bbuf[(size_t)b * CAP + i] >> 17], 1);
    __syncthreads();
    int v = deg[t];
    int sv2 = wave_incl_scan_i(v);
    if (lane == 63) wsum2[wid] = sv2;
    __syncthreads();
    if (t == 0) {
      int r = 0;
#pragma unroll
      for (int k = 0; k < 4; k++) { int x2 = wsum2[k]; wsum2[k] = r; r += x2; }
    }
    __syncthreads();
    int excl2 = wsum2[wid] + sv2 - v;
    int node = (b << BSH) + t;
    if (node < N) offs[node] = ebeg + excl2;
    if (b == 0 && t == 0) offs[N] = sst[512];
    __syncthreads();
    deg[t] = excl2;
    __syncthreads();
    for (int i = t; i < cnt; i += BSZ) {
      uint rec = bbuf[(size_t)b * CAP + i];
      int r = atomicAdd(&deg[rec >> 17], 1);
      ssrc[ebeg + r] = (int)(rec & 0x1FFFF);
    }
    return;
  }
  // ---- gemm1 path (operand-swapped MFMA: D[channel][node]) ----
  int bid = blockIdx.x - NB;
  int wv = threadIdx.x >> 6, l = threadIdx.x & 63;
  int lg = l >> 4, lr = l & 15;
  int row0 = bid * 64 + wv * 16;
  int node = row0 + lr;
  bool valid = node < N;
  float sc = valid ? nw[node] : 0.f;
  bf16x8 xfr[4];
  const float* xr = x + (size_t)node * 128;
#pragma unroll
  for (int kc = 0; kc < 4; kc++) {
    float v[8];
    if (valid) {
      float4 q0 = *reinterpret_cast<const float4*>(xr + kc * 32 + lg * 8);
      float4 q1 = *reinterpret_cast<const float4*>(xr + kc * 32 + lg * 8 + 4);
      v[0] = q0.x; v[1] = q0.y; v[2] = q0.z; v[3] = q0.w;
      v[4] = q1.x; v[5] = q1.y; v[6] = q1.z; v[7] = q1.w;
    } else {
#pragma unroll
      for (int j = 0; j < 8; j++) v[j] = 0.f;
    }
    U4B a;
    uint pk0 = (uint)f2bf(v[0] * sc) | ((uint)f2bf(v[1] * sc) << 16);
    uint pk1 = (uint)f2bf(v[2] * sc) | ((uint)f2bf(v[3] * sc) << 16);
    uint pk2 = (uint)f2bf(v[4] * sc) | ((uint)f2bf(v[5] * sc) << 16);
    uint pk3 = (uint)f2bf(v[6] * sc) | ((uint)f2bf(v[7] * sc) << 16);
    a.u = make_uint4(pk0, pk1, pk2, pk3);
    xfr[kc] = a.v;
  }
  float pS[4] = {}, pD[4] = {};
#pragma unroll
  for (int ct = 0; ct < 8; ct++) {
    f32x4 acc = {0.f, 0.f, 0.f, 0.f};
    const ushort* wrow = Wt + (size_t)(ct * 16 + lr) * 128;
#pragma unroll
    for (int kc = 0; kc < 4; kc++) {
      U4B bfr;
      bfr.u = *reinterpret_cast<const uint4*>(wrow + kc * 32 + lg * 8);
      acc = __builtin_amdgcn_mfma_f32_16x16x32_bf16(bfr.v, xfr[kc], acc, 0, 0, 0);
    }
    int c0 = ct * 16 + lg * 4;
    if (valid) {
      uint u8 = (uint)__builtin_amdgcn_cvt_pk_fp8_f32(acc[0], acc[1], 0, false);
      u8 = (uint)__builtin_amdgcn_cvt_pk_fp8_f32(acc[2], acc[3], u8, true);
      *reinterpret_cast<uint*>(hb1 + (size_t)node * 128 + c0) = u8;
    }
    float4 as4 = *reinterpret_cast<const float4*>(att_s + c0);
    float4 ad4 = *reinterpret_cast<const float4*>(att_d + c0);
    int h = ct >> 1;
    pS[h] += acc[0] * as4.x + acc[1] * as4.y + acc[2] * as4.z + acc[3] * as4.w;
    pD[h] += acc[0] * ad4.x + acc[1] * ad4.y + acc[2] * ad4.z + acc[3] * ad4.w;
  }
#pragma unroll
  for (int off = 16; off < 64; off <<= 1) {
#pragma unroll
    for (int h = 0; h < 4; h++) {
      pS[h] += __shfl_xor(pS[h], off, 64);
      pD[h] += __shfl_xor(pD[h], off, 64);
    }
  }
  if (lg == 0 && valid) {
    *reinterpret_cast<float4*>(asrc + node * 4) = make_float4(pS[0], pS[1], pS[2], pS[3]);
    *reinterpret_cast<float4*>(adst + node * 4) = make_float4(pD[0], pD[1], pD[2], pD[3]);
  }
}

// ---- fused layer-1 aggregation + layer-2 GEMM (MFMA, wave-0 tail) + att2 ----
__global__ void k_aggr1(const int* __restrict__ offs, const int* __restrict__ ssrc,
                        const uchar* __restrict__ hb, const float* __restrict__ asrc,
                        const float* __restrict__ adst, const float* __restrict__ bias,
                        const ushort* __restrict__ Wt2, const float* __restrict__ as2,
                        const float* __restrict__ ad2, uchar* __restrict__ hb2,
                        float* __restrict__ asrc2, float* __restrict__ adst2, int N) {
  __shared__ ushort rowl[4][136];    // bf16 out1 rows, +8 pad
  int tid = threadIdx.x;
  int wv = tid >> 6, l = tid & 63;
  int d = blockIdx.x * 4 + wv;
  int dc = min(d, N - 1);
  int slot = l >> 3;       // 0..7 edge slot
  int cb = l & 7;          // channel block: ch cb*16 .. +15
  int h = cb >> 1;         // head of this lane's channels
  float ad = adst[dc * 4 + h];
  int beg = offs[dc], end = offs[dc + 1];
  float a[16] = {};
  float ds = 0.f;
  for (int i = beg; i < end; i += 8) {
    int e = i + slot;
    int ec = min(e, end - 1);
    int s = ssrc[ec];
    float xv = asrc[s * 4 + h] + ad;
    xv = xv > 0.f ? xv : NEG * xv;
    float w = __expf(xv);
    w = (e < end) ? w : 0.f;
    uint4 p = *reinterpret_cast<const uint4*>(hb + (size_t)s * 128 + cb * 16);
    uint pu[4] = {p.x, p.y, p.z, p.w};
#pragma unroll
    for (int q = 0; q < 4; q++) {
      f32x2 f0 = __builtin_amdgcn_cvt_pk_f32_fp8(pu[q], false);
      f32x2 f1 = __builtin_amdgcn_cvt_pk_f32_fp8(pu[q], true);
      a[q * 4 + 0] += w * f0.x;
      a[q * 4 + 1] += w * f0.y;
      a[q * 4 + 2] += w * f1.x;
      a[q * 4 + 3] += w * f1.y;
    }
    ds += w;
  }
  int b3 = (l >> 3) & 1, b4 = (l >> 4) & 1, b5 = (l >> 5) & 1;
  float t8[8];
#pragma unroll
  for (int r = 0; r < 8; r++) {
    float send = b3 ? a[r] : a[r + 8];
    float recv = __shfl_xor(send, 8, 64);
    t8[r] = (b3 ? a[r + 8] : a[r]) + recv;
  }
  float t4[4];
#pragma unroll
  for (int r = 0; r < 4; r++) {
    float send = b4 ? t8[r] : t8[r + 4];
    float recv = __shfl_xor(send, 16, 64);
    t4[r] = (b4 ? t8[r + 4] : t8[r]) + recv;
  }
  float t2[2];
#pragma unroll
  for (int r = 0; r < 2; r++) {
    float send = b5 ? t4[r] : t4[r + 2];
    float recv = __shfl_xor(send, 32, 64);
    t2[r] = (b5 ? t4[r + 2] : t4[r]) + recv;
  }
  ds += __shfl_xor(ds, 8, 64);
  ds += __shfl_xor(ds, 16, 64);
  ds += __shfl_xor(ds, 32, 64);
  float inv = 1.f / (ds > 0.f ? ds : 1.f);
  int c0 = cb * 16 + b3 * 8 + b4 * 4 + b5 * 2;
  float r0 = t2[0] * inv + bias[c0];
  float r1 = t2[1] * inv + bias[c0 + 1];
  r0 = r0 > 0.f ? r0 : expm1f(r0);
  r1 = r1 > 0.f ? r1 : expm1f(r1);
  *reinterpret_cast<uint*>(&rowl[wv][c0]) = (uint)f2bf(r0) | ((uint)f2bf(r1) << 16);
  __syncthreads();
  if (wv != 0) return;
  // ---- gemm2 + att2 on the block's 4 rows (wave 0 only) ----
  int lg = l >> 4, lr = l & 15;
  int rsel = lr & 3;
  bf16x8 bfrag[4];
#pragma unroll
  for (int kc = 0; kc < 4; kc++) {
    U4B bb;
    bb.u = *reinterpret_cast<const uint4*>(&rowl[rsel][kc * 32 + lg * 8]);
    bfrag[kc] = bb.v;
  }
  int dd = blockIdx.x * 4 + lr;      // valid only for lr<4
  bool vs = (lr < 4) && (dd < N);
  float pS = 0.f, pD = 0.f;
#pragma unroll
  for (int ct = 0; ct < 2; ct++) {
    f32x4 acc = {0.f, 0.f, 0.f, 0.f};
    const ushort* wrow = Wt2 + (size_t)(ct * 16 + lr) * 128;
#pragma unroll
    for (int kc = 0; kc < 4; kc++) {
      U4B bfr;
      bfr.u = *reinterpret_cast<const uint4*>(wrow + kc * 32 + lg * 8);
      acc = __builtin_amdgcn_mfma_f32_16x16x32_bf16(bfr.v, bfrag[kc], acc, 0, 0, 0);
    }
    int cg = ct * 16 + lg * 4;
    if (vs) {
      uint u8 = (uint)__builtin_amdgcn_cvt_pk_fp8_f32(acc[0], acc[1], 0, false);
      u8 = (uint)__builtin_amdgcn_cvt_pk_fp8_f32(acc[2], acc[3], u8, true);
      *reinterpret_cast<uint*>(hb2 + (size_t)dd * 32 + cg) = u8;
    }
    float4 as4 = *reinterpret_cast<const float4*>(as2 + cg);
    float4 ad4 = *reinterpret_cast<const float4*>(ad2 + cg);
    pS += acc[0] * as4.x + acc[1] * as4.y + acc[2] * as4.z + acc[3] * as4.w;
    pD += acc[0] * ad4.x + acc[1] * ad4.y + acc[2] * ad4.z + acc[3] * ad4.w;
  }
  pS += __shfl_xor(pS, 16, 64);
  pS += __shfl_xor(pS, 32, 64);
  pD += __shfl_xor(pD, 16, 64);
  pD += __shfl_xor(pD, 32, 64);
  if (vs && lg == 0) { asrc2[dd] = pS; adst2[dd] = pD; }
}

// ---- layer-2 aggregation: wave/dst, 16 slots x 4 lanes x uint2 (full 32B row per edge) ----
__global__ void k_aggr2(const int* __restrict__ offs, const int* __restrict__ ssrc,
                        const uchar* __restrict__ hb, const float* __restrict__ asrc,
                        const float* __restrict__ adst, const float* __restrict__ bias,
                        float* __restrict__ out, int N) {
  int wid = threadIdx.x >> 6, l = threadIdx.x & 63;
  int d = blockIdx.x * 4 + wid;
  if (d >= N) return;
  int slot = l >> 2;       // 0..15 edge slot
  int k = l & 3;           // channel block: ch k*8 .. +7
  float ad = adst[d];
  int beg = offs[d], end = offs[d + 1];
  float a[8] = {};
  float ds = 0.f;
  for (int i = beg; i < end; i += 16) {
    int e = i + slot;
    int ec = min(e, end - 1);
    int s = ssrc[ec];
    float xv = asrc[s] + ad;
    xv = xv > 0.f ? xv : NEG * xv;
    float w = __expf(xv);
    w = (e < end) ? w : 0.f;
    uint2 p = *reinterpret_cast<const uint2*>(hb + (size_t)s * 32 + k * 8);
    f32x2 f0 = __builtin_amdgcn_cvt_pk_f32_fp8(p.x, false);
    f32x2 f1 = __builtin_amdgcn_cvt_pk_f32_fp8(p.x, true);
    f32x2 f2 = __builtin_amdgcn_cvt_pk_f32_fp8(p.y, false);
    f32x2 f3 = __builtin_amdgcn_cvt_pk_f32_fp8(p.y, true);
    a[0] += w * f0.x; a[1] += w * f0.y; a[2] += w * f1.x; a[3] += w * f1.y;
    a[4] += w * f2.x; a[5] += w * f2.y; a[6] += w * f3.x; a[7] += w * f3.y;
    ds += w;
  }
  int b2 = (l >> 2) & 1, b3 = (l >> 3) & 1, b4 = (l >> 4) & 1;
  float t4[4];
#pragma unroll
  for (int r = 0; r < 4; r++) {
    float send = b2 ? a[r] : a[r + 4];
    float recv = __shfl_xor(send, 4, 64);
    t4[r] = (b2 ? a[r + 4] : a[r]) + recv;
  }
  float t2[2];
#pragma unroll
  for (int r = 0; r < 2; r++) {
    float send = b3 ? t4[r] : t4[r + 2];
    float recv = __shfl_xor(send, 8, 64);
    t2[r] = (b3 ? t4[r + 2] : t4[r]) + recv;
  }
  float send = b4 ? t2[0] : t2[1];
  float recv = __shfl_xor(send, 16, 64);
  float t1 = (b4 ? t2[1] : t2[0]) + recv;
  t1 += __shfl_xor(t1, 32, 64);
  ds += __shfl_xor(ds, 4, 64);
  ds += __shfl_xor(ds, 8, 64);
  ds += __shfl_xor(ds, 16, 64);
  ds += __shfl_xor(ds, 32, 64);
  if (l < 32) {
    int c = k * 8 + b2 * 4 + b3 * 2 + b4;
    float r = t1 / ds + bias[c];
    r = r > 0.f ? r : expm1f(r);
    out[(size_t)d * 32 + c] = r;
  }
}

// ---------------- pool (mean per graph, batch sorted) + FC ----------------
__global__ void k_pool_fc(const float* __restrict__ h2, const int* __restrict__ batch,
                          const float* __restrict__ fcW, const float* __restrict__ fcb,
                          float* __restrict__ out, int N) {
  int g = blockIdx.x;
  int lo = 0, hi = N;
  while (lo < hi) { int mid = (lo + hi) >> 1; if (batch[mid] < g) lo = mid + 1; else hi = mid; }
  int beg = lo;
  hi = N;
  while (lo < hi) { int mid = (lo + hi) >> 1; if (batch[mid] < g + 1) lo = mid + 1; else hi = mid; }
  int end = lo;
  int t = threadIdx.x, c = t & 31, sub = t >> 5;
  float acc = 0.f;
  for (int n = beg + sub; n < end; n += 8) acc += h2[(size_t)n * 32 + c];
  __shared__ float red[8][32];
  __shared__ float pooled[32];
  red[sub][c] = acc;
  __syncthreads();
  if (sub == 0) {
    float s = 0.f;
#pragma unroll
    for (int i = 0; i < 8; i++) s += red[i][c];
    float cnt = (float)(end - beg);
    pooled[c] = s / fmaxf(cnt, 1.f);
  }
  __syncthreads();
  if (t < 16) {
    float r = fcb[t];
#pragma unroll
    for (int cc = 0; cc < 32; cc++) r += pooled[cc] * fcW[cc * 16 + t];
    out[g * 16 + t] = r;
  }
}

// ---------------- host launch ----------------
extern "C" void kernel_launch(void* const* d_in, const int* in_sizes, int n_in,
                              void* d_out, int out_size, void* d_ws, size_t ws_size,
                              hipStream_t stream) {
  const float* x     = (const float*)d_in[0];
  const int*   ei    = (const int*)d_in[1];
  const int*   batch = (const int*)d_in[2];
  const float* nw    = (const float*)d_in[3];
  const float* W1    = (const float*)d_in[4];
  const float* as1w  = (const float*)d_in[5];
  const float* ad1w  = (const float*)d_in[6];
  const float* b1    = (const float*)d_in[7];
  const float* W2    = (const float*)d_in[8];
  const float* as2w  = (const float*)d_in[9];
  const float* ad2w  = (const float*)d_in[10];
  const float* b2    = (const float*)d_in[11];
  const float* fcW   = (const float*)d_in[12];
  const float* fcb   = (const float*)d_in[13];
  float* out = (float*)d_out;

  const int N = in_sizes[0] / 128;
  const int E = in_sizes[1] / 2;
  const int Etot = E + N;
  const int NB = (N + BSZ - 1) >> BSH;

  char* w = (char*)d_ws;
  size_t ofs = 0;
  auto alloc = [&](size_t bytes) {
    char* p = w + ofs;
    ofs += (bytes + 255) & ~(size_t)255;
    return p;
  };
  uchar*  hb1    = (uchar*)alloc((size_t)N * 128);        // fp8 layer-1 features
  uchar*  hb2    = (uchar*)alloc((size_t)N * 32);         // fp8 layer-2 features
  float*  h2     = (float*)alloc((size_t)N * 32 * 4);     // fp32 layer-2 output
  float*  asrc1  = (float*)alloc((size_t)N * 4 * 4);
  float*  adst1  = (float*)alloc((size_t)N * 4 * 4);
  float*  asrc2  = (float*)alloc((size_t)N * 4);
  float*  adst2  = (float*)alloc((size_t)N * 4);
  ushort* Wt1    = (ushort*)alloc(16384 * 2);
  ushort* Wt2    = (ushort*)alloc(4096 * 2);
  int*    bcur   = (int*)alloc((size_t)NB * 4);
  int*    offs   = (int*)alloc((size_t)(N + 1) * 4);
  uint*   bbuf   = (uint*)alloc((size_t)NB * CAP * 4);
  int*    ssrc   = (int*)alloc((size_t)Etot * 4);

  hipMemsetAsync(bcur, 0, (size_t)NB * 4, stream);

  // binned CSR: hist+scatter (+W1/W2 prep folded in)
  const int nbin = (Etot + 4095) / 4096;
  k_bin<<<nbin + 80, 256, 0, stream>>>(ei, W1, W2, Wt1, Wt2, E, Etot, NB, nbin, bcur, bbuf);

  // build ‖ gemm1 (independent): blocks [0,NB) build CSR, rest run GEMM1+att1
  const int ngemm1 = (N + 63) / 64;
  k_bg<<<NB + ngemm1, 256, 0, stream>>>(bbuf, bcur, NB, N, offs, ssrc,
                                        x, Wt1, nw, as1w, ad1w, hb1, asrc1, adst1);

  // fused: layer-1 aggregation + layer-2 GEMM (MFMA) + att2
  k_aggr1<<<(N + 3) / 4, 256, 0, stream>>>(offs, ssrc, hb1, asrc1, adst1, b1,
                                           Wt2, as2w, ad2w, hb2, asrc2, adst2, N);

  // layer-2 aggregation
  k_aggr2<<<(N + 3) / 4, 256, 0, stream>>>(offs, ssrc, hb2, asrc2, adst2, b2, h2, N);

  // pool + fc
  k_pool_fc<<<NGRAPH, 256, 0, stream>>>(h2, batch, fcW, fcb, out, N);
}